// Round 8
// baseline (542.001 us; speedup 1.0000x reference)
//
#include <hip/hip_runtime.h>
#include <stdint.h>

typedef __bf16 bf16;
typedef __attribute__((ext_vector_type(8))) __bf16 bf16x8;
typedef __attribute__((ext_vector_type(4))) float f32x4;

#define LORA_SCALE 0.25f

// async global->LDS, 16B per lane. LDS dest is wave-uniform base + lane*16.
__device__ __forceinline__ void gload_lds16(const bf16* g, bf16* l) {
    __builtin_amdgcn_global_load_lds(
        (const __attribute__((address_space(1))) uint32_t*)g,
        (__attribute__((address_space(3))) uint32_t*)l,
        16, 0, 0);
}

__device__ __forceinline__ bf16x8 cvt8(const float* p) {
    f32x4 a = *(const f32x4*)p;
    f32x4 b = *(const f32x4*)(p + 4);
    bf16x8 r;
    r[0] = (bf16)a[0]; r[1] = (bf16)a[1]; r[2] = (bf16)a[2]; r[3] = (bf16)a[3];
    r[4] = (bf16)b[0]; r[5] = (bf16)b[1]; r[6] = (bf16)b[2]; r[7] = (bf16)b[3];
    return r;
}

// Convert W1 (n1 elems) and W2 (n2 elems) f32->bf16 in one launch.
__global__ __launch_bounds__(256)
void cvt_weights(const float* __restrict__ in1, bf16* __restrict__ out1, int n1,
                 const float* __restrict__ in2, bf16* __restrict__ out2, int n2) {
    const int64_t idx = (int64_t)(blockIdx.x * 256 + threadIdx.x) * 8;
    if (idx < n1) *(bf16x8*)&out1[idx] = cvt8(&in1[idx]);
    else          *(bf16x8*)&out2[idx - n1] = cvt8(&in2[idx - n1]);
}

// t1[m][r] = sum_k X[m][k] * Aall[aid][r][k]. 4 rows per wave. Also writes
// Xb = bf16(X). K=1024. Grid: M/16 blocks of 256.
__global__ __launch_bounds__(256)
void lora1(const float* __restrict__ X, const float* __restrict__ Aall,
           const int* __restrict__ adapter, float* __restrict__ T,
           bf16* __restrict__ Xb)
{
    const int K = 1024;
    const int gid = blockIdx.x * 256 + threadIdx.x;
    const int aid = adapter[0];
    const float* Aa = Aall + (int64_t)aid * 4 * K;
    const int wid  = gid >> 6;
    const int lane = threadIdx.x & 63;
    const int m0   = wid * 4;

    float acc[4][4];
    #pragma unroll
    for (int rr = 0; rr < 4; rr++)
        #pragma unroll
        for (int r = 0; r < 4; r++) acc[rr][r] = 0.f;

    #pragma unroll
    for (int it = 0; it < K / 512; it++) {
        const int k = it * 512 + lane * 8;
        float av[4][8];
        #pragma unroll
        for (int r = 0; r < 4; r++) {
            f32x4 a = *(const f32x4*)&Aa[r * K + k];
            f32x4 b = *(const f32x4*)&Aa[r * K + k + 4];
            av[r][0]=a[0]; av[r][1]=a[1]; av[r][2]=a[2]; av[r][3]=a[3];
            av[r][4]=b[0]; av[r][5]=b[1]; av[r][6]=b[2]; av[r][7]=b[3];
        }
        #pragma unroll
        for (int rr = 0; rr < 4; rr++) {
            const float* xp = X + (int64_t)(m0 + rr) * K + k;
            f32x4 a = *(const f32x4*)xp;
            f32x4 b = *(const f32x4*)(xp + 4);
            float xv[8] = {a[0],a[1],a[2],a[3],b[0],b[1],b[2],b[3]};
            bf16x8 xb;
            #pragma unroll
            for (int e = 0; e < 8; e++) xb[e] = (bf16)xv[e];
            *(bf16x8*)&Xb[(int64_t)(m0 + rr) * K + k] = xb;
            #pragma unroll
            for (int r = 0; r < 4; r++)
                #pragma unroll
                for (int e = 0; e < 8; e++)
                    acc[rr][r] += xv[e] * av[r][e];
        }
    }
    #pragma unroll
    for (int rr = 0; rr < 4; rr++)
        #pragma unroll
        for (int r = 0; r < 4; r++)
            #pragma unroll
            for (int off = 32; off >= 1; off >>= 1)
                acc[rr][r] += __shfl_xor(acc[rr][r], off);
    if (lane == 0) {
        #pragma unroll
        for (int rr = 0; rr < 4; rr++) {
            f32x4 t;
            t[0] = acc[rr][0]; t[1] = acc[rr][1]; t[2] = acc[rr][2]; t[3] = acc[rr][3];
            *(f32x4*)&T[(int64_t)(m0 + rr) * 4] = t;
        }
    }
}

// t2[m][r] = sum_p T2p[p][m][r], p < NP. One thread per (m,r).
__global__ __launch_bounds__(256)
void t2_reduce(const float* __restrict__ T2p, float* __restrict__ T2,
               int M, int NP) {
    const int i = blockIdx.x * 256 + threadIdx.x;   // (m*4 + r)
    float s = 0.f;
    for (int p = 0; p < NP; p++) s += T2p[(int64_t)p * M * 4 + i];
    T2[i] = s;
}

#define MFMA16(AF, BF, JOFF)                                                     \
    __builtin_amdgcn_s_setprio(1);                                              \
    _Pragma("unroll")                                                            \
    for (int mi = 0; mi < 4; mi++)                                               \
        _Pragma("unroll")                                                        \
        for (int j = 0; j < 4; j++)                                              \
            acc[mi][JOFF + j] = __builtin_amdgcn_mfma_f32_16x16x32_bf16(         \
                AF[mi], BF[j], acc[mi][JOFF + j], 0, 0, 0);                      \
    __builtin_amdgcn_s_setprio(0);

// C[m][n] = act( sum_k A[m][k]*Bm[n][k] + SCALE * sum_r Tlo[m][r]*Blo[aid][n][r] )
//
// R8: PERSISTENT sub-tiles. R6 proved this exact 4-phase K-loop runs at
// 4406 cyc/tile (56% MfmaUtil) when a block owns its CU for many tiles
// (D1), but real gemm1 paid 6844 cyc/tile across 4 sequential dispatch
// rounds: ~65 us = 4x(fill + epilogue + inter-block gap). Occupancy can't
// fix it (acc = 128 AGPR + 128 VGPR = 256/thread -> hard 8 waves/CU).
// So: grid = 256 blocks (1 round), each block sweeps NSUB bx-subtiles at
// fixed by. Sub boundary: issue next-sub buf0 stages -> epilogue (scratch
// in the buf1 half; buf1 is staged only AFTER a barrier) -> stage buf1 ->
// vmcnt(6) -> barrier -> next K-loop. Fill hides under the epilogue; 3 of
// 4 fills + all inter-block gaps vanish. A-panel now read by one XCD only.
template<bool RELU, typename CT, bool FUSET2, int NSUB>
__global__ __launch_bounds__(512, 2)
void gemm_p(const bf16* __restrict__ A,    // [M][K] bf16
            const bf16* __restrict__ Bm,   // [N][K] bf16 (torch [out,in])
            CT* __restrict__ C,            // [M][N]
            const float* __restrict__ Tlo, // [M][4]
            const float* __restrict__ Blo, // [NUM][N][4] f32
            const int* __restrict__ adapter,
            const float* __restrict__ A2,  // [NUM][4][N] f32 (FUSET2)
            float* __restrict__ T2p,       // [2*NxTiles][M][4] (FUSET2)
            int M, int N, int K)
{
    __shared__ alignas(16) bf16 smem[65536];   // 128 KB

    const int tid  = threadIdx.x;
    const int lane = tid & 63;
    const int w    = tid >> 6;
    const int quad = lane >> 4;
    const int l16  = lane & 15;

    // Remap: xcd = id&7; each XCD owns contiguous by-band; the nGrp blocks
    // sharing a by (bx0 groups) are consecutive k -> SAME xcd -> A-panel
    // fetched once per XCD. Bijective (grid = 8 * q * nGrp).
    int bx, by;
    {
        const int id = blockIdx.y * gridDim.x + blockIdx.x;
        const int xcd = id & 7, k = id >> 3;
        const int nGrp = gridDim.x;            // N/(256*NSUB)
        const int q = gridDim.y >> 3;          // Mt/8
        by = xcd * q + (k / nGrp);
        bx = (k % nGrp) * NSUB;
    }
    const int mBase = by * 256;
    const int wm = (w >> 1) * 64;              // 0/64/128/192
    const int wn = (w & 1) * 128;              // 0/128

    f32x4 acc[4][8];

    const bf16* gA = A + (int64_t)mBase * K;
    const int sq   = (tid & 3) ^ ((tid >> 3) & 3);
    const int srow = ((tid >> 3) << 1) | ((tid >> 2) & 1);
    const bf16* sA0 = gA + (int64_t)srow * K + sq * 8;
    const bf16* sA1 = gA + (int64_t)(srow + 128) * K + sq * 8;
    const int dstW = w * 512;                  // wave-uniform LDS base (elems)

    const bf16* gB = Bm + (int64_t)bx * 256 * K;
    const bf16* sB0 = gB + (int64_t)srow * K + sq * 8;
    const bf16* sB1 = gB + (int64_t)(srow + 128) * K + sq * 8;

    // fragment reads: row = (wm|wn) + f*16 + l16; phys chunk = quad ^ ((l16>>1)&3)
    const int pc8  = (quad ^ ((l16 >> 1) & 3)) * 8;
    const int aOff = (wm + l16) * 32 + pc8;
    const int bOff = (wn + l16) * 32 + pc8;

    const int NT = K >> 6;

    // unit u of buffer b at smem + (b*4+u)*8192 elems; co = elem offset in K.
    auto stageU = [&](const bf16* s0, const bf16* s1, int buf, int uidx, int co) {
        bf16* u = smem + (buf * 4 + uidx) * 8192;
        gload_lds16(s0 + co, u + dstW);
        gload_lds16(s1 + co, u + dstW + 4096);
    };

    // ---- prologue (sub 0): tile0 -> buf0, tile1 u0..u2 -> buf1
    stageU(sA0, sA1, 0, 0, 0);  stageU(sB0, sB1, 0, 1, 0);
    stageU(sA0, sA1, 0, 2, 32); stageU(sB0, sB1, 0, 3, 32);
    stageU(sA0, sA1, 1, 0, 64); stageU(sB0, sB1, 1, 1, 64);
    stageU(sA0, sA1, 1, 2, 96);
    asm volatile("s_waitcnt vmcnt(6)" ::: "memory");
    __builtin_amdgcn_s_barrier();
    __builtin_amdgcn_sched_barrier(0);

    bf16x8 aX[4], aY[4], bX[4], bY[4];
    #pragma unroll
    for (int i = 0; i < 4; i++) aX[i] = *(const bf16x8*)&smem[aOff + i * 512];
    #pragma unroll
    for (int j = 0; j < 4; j++) bX[j] = *(const bf16x8*)&smem[8192 + bOff + j * 512];

    const int aid = adapter[0];
    const float* Ba  = Blo + (int64_t)aid * N * 4;
    const float* A2a = FUSET2 ? A2 + (int64_t)aid * 4 * N : nullptr;

    #pragma unroll 1
    for (int sub = 0; sub < NSUB; ++sub) {
        #pragma unroll
        for (int i = 0; i < 4; i++)
            #pragma unroll
            for (int j = 0; j < 8; j++)
                #pragma unroll
                for (int e = 0; e < 4; e++) acc[i][j][e] = 0.f;

        // ================= K-loop (R6-verified 4-phase, 56% steady) ========
        for (int t = 0; t < NT; ++t) {
            const bf16* ub = smem + (t & 1) * 32768;
            const bf16* u1 = ub + 8192;
            const bf16* u2 = ub + 16384;
            const bf16* u3 = ub + 24576;
            const bf16* n0 = smem + ((t + 1) & 1) * 32768;
            const bf16* n1 = n0 + 8192;
            const bool sNext  = (t + 1 < NT);
            const bool sNext2 = (t + 2 < NT);

            // ---- phase 0
            asm volatile("s_waitcnt lgkmcnt(0)" ::: "memory");
            __builtin_amdgcn_sched_barrier(0);
            #pragma unroll
            for (int j = 0; j < 4; j++) bY[j] = *(const bf16x8*)&u1[bOff + (4 + j) * 512];
            if (sNext) stageU(sB0, sB1, (t + 1) & 1, 3, (t + 1) * 64 + 32);
            MFMA16(aX, bX, 0)
            __builtin_amdgcn_s_barrier();
            __builtin_amdgcn_sched_barrier(0);

            // ---- phase 1
            asm volatile("s_waitcnt lgkmcnt(0)" ::: "memory");
            __builtin_amdgcn_sched_barrier(0);
            #pragma unroll
            for (int i = 0; i < 4; i++) aY[i] = *(const bf16x8*)&u2[aOff + i * 512];
            #pragma unroll
            for (int j = 0; j < 4; j++) bX[j] = *(const bf16x8*)&u3[bOff + j * 512];
            if (sNext2) stageU(sA0, sA1, t & 1, 0, (t + 2) * 64);
            MFMA16(aX, bY, 4)
            __builtin_amdgcn_s_barrier();
            __builtin_amdgcn_sched_barrier(0);

            // ---- phase 2
            asm volatile("s_waitcnt lgkmcnt(0)" ::: "memory");
            __builtin_amdgcn_sched_barrier(0);
            #pragma unroll
            for (int j = 0; j < 4; j++) bY[j] = *(const bf16x8*)&u3[bOff + (4 + j) * 512];
            if (sNext2) stageU(sB0, sB1, t & 1, 1, (t + 2) * 64);
            if (sNext2)      asm volatile("s_waitcnt vmcnt(4)" ::: "memory");
            else if (sNext)  asm volatile("s_waitcnt vmcnt(0)" ::: "memory");
            MFMA16(aY, bX, 0)
            __builtin_amdgcn_s_barrier();      // publishes tile t+1
            __builtin_amdgcn_sched_barrier(0);

            // ---- phase 3
            asm volatile("s_waitcnt lgkmcnt(0)" ::: "memory");
            __builtin_amdgcn_sched_barrier(0);
            if (t + 1 < NT) {
                #pragma unroll
                for (int i = 0; i < 4; i++) aX[i] = *(const bf16x8*)&n0[aOff + i * 512];
                #pragma unroll
                for (int j = 0; j < 4; j++) bX[j] = *(const bf16x8*)&n1[bOff + j * 512];
            }
            if (sNext2) stageU(sA0, sA1, t & 1, 2, (t + 2) * 64 + 32);
            MFMA16(aY, bY, 4)
            __builtin_amdgcn_s_barrier();
            __builtin_amdgcn_sched_barrier(0);
        }
        // Loop exit invariants: vmcnt == 0 (full drain at t=NT-2 ph2; NT-1
        // stages nothing), all waves past the final barrier, LDS quiescent.

        const int nBase = bx * 256;

        // ---- issue next-sub tile0 -> buf0 BEFORE the epilogue (fill hides)
        const bf16 *nB0 = nullptr, *nB1 = nullptr;
        if (sub + 1 < NSUB) {
            const bf16* gBn = Bm + (int64_t)(bx + 1) * 256 * K;
            nB0 = gBn + (int64_t)srow * K + sq * 8;
            nB1 = gBn + (int64_t)(srow + 128) * K + sq * 8;
            stageU(sA0, sA1, 0, 0, 0);  stageU(nB0, nB1, 0, 1, 0);
            stageU(sA0, sA1, 0, 2, 32); stageU(nB0, nB1, 0, 3, 32);
        }

        // ---- epilogue for (bx, by). Scratch lives in the buf1 half
        // [32768, 65536): staged only AFTER the __syncthreads below.
        f32x4 bv[8];
        #pragma unroll
        for (int j = 0; j < 8; j++) {
            const int f = nBase + wn + j * 16 + l16;
            bv[j] = *(const f32x4*)&Ba[(int64_t)f * 4];
        }
        float a2v[8][4];
        if constexpr (FUSET2) {
            #pragma unroll
            for (int j = 0; j < 8; j++) {
                const int f = nBase + wn + j * 16 + l16;
                #pragma unroll
                for (int r2 = 0; r2 < 4; r2++)
                    a2v[j][r2] = A2a[(int64_t)r2 * N + f];
            }
        }
        float* T2row = FUSET2 ? T2p + (int64_t)(bx * 2 + (w & 1)) * M * 4 : nullptr;

        if constexpr (sizeof(CT) == 2) {
            bf16* scratch = smem + 32768 + w * (16 * 136);   // buf1 half
            #pragma unroll
            for (int mi = 0; mi < 4; mi++) {
                f32x4 tv[4];
                #pragma unroll
                for (int r = 0; r < 4; r++) {
                    const int m = mBase + wm + mi * 16 + quad * 4 + r;
                    tv[r] = *(const f32x4*)&Tlo[(int64_t)m * 4];
                }
                float tp[4][4];
                if constexpr (FUSET2)
                    #pragma unroll
                    for (int r = 0; r < 4; r++)
                        #pragma unroll
                        for (int r2 = 0; r2 < 4; r2++) tp[r][r2] = 0.f;
                #pragma unroll
                for (int j = 0; j < 8; j++) {
                    #pragma unroll
                    for (int r = 0; r < 4; r++) {
                        const float d = tv[r][0] * bv[j][0] + tv[r][1] * bv[j][1]
                                      + tv[r][2] * bv[j][2] + tv[r][3] * bv[j][3];
                        float v = acc[mi][j][r] + LORA_SCALE * d;
                        if (RELU) v = v > 0.f ? v : 0.f;
                        if constexpr (FUSET2)
                            #pragma unroll
                            for (int r2 = 0; r2 < 4; r2++) tp[r][r2] += v * a2v[j][r2];
                        scratch[(quad * 4 + r) * 136 + j * 16 + l16] = (bf16)v;
                    }
                }
                if constexpr (FUSET2) {
                    #pragma unroll
                    for (int r = 0; r < 4; r++)
                        #pragma unroll
                        for (int r2 = 0; r2 < 4; r2++)
                            #pragma unroll
                            for (int off = 8; off >= 1; off >>= 1)
                                tp[r][r2] += __shfl_xor(tp[r][r2], off);
                    if (l16 == 0) {
                        #pragma unroll
                        for (int r = 0; r < 4; r++) {
                            const int m = mBase + wm + mi * 16 + quad * 4 + r;
                            f32x4 o;
                            o[0] = tp[r][0]; o[1] = tp[r][1];
                            o[2] = tp[r][2]; o[3] = tp[r][3];
                            *(f32x4*)&T2row[(int64_t)m * 4] = o;
                        }
                    }
                }
                #pragma unroll
                for (int it = 0; it < 4; it++) {
                    const int cid = it * 64 + lane;
                    const int row = cid >> 4, c8 = cid & 15;
                    bf16x8 vv = *(const bf16x8*)&scratch[row * 136 + c8 * 8];
                    const int m = mBase + wm + mi * 16 + row;
                    *(bf16x8*)&C[(int64_t)m * N + nBase + wn + c8 * 8] = vv;
                }
            }
        } else {
            // f32 path used only with NSUB==1 (no staging in flight) ->
            // scratch may use the base region.
            float* scratchf = (float*)smem + w * (16 * 132);
            #pragma unroll
            for (int mi = 0; mi < 4; mi++) {
                f32x4 tv[4];
                #pragma unroll
                for (int r = 0; r < 4; r++) {
                    const int m = mBase + wm + mi * 16 + quad * 4 + r;
                    tv[r] = *(const f32x4*)&Tlo[(int64_t)m * 4];
                }
                #pragma unroll
                for (int j = 0; j < 8; j++) {
                    #pragma unroll
                    for (int r = 0; r < 4; r++) {
                        const float d = tv[r][0] * bv[j][0] + tv[r][1] * bv[j][1]
                                      + tv[r][2] * bv[j][2] + tv[r][3] * bv[j][3];
                        float v = acc[mi][j][r] + LORA_SCALE * d;
                        if (RELU) v = v > 0.f ? v : 0.f;
                        scratchf[(quad * 4 + r) * 132 + j * 16 + l16] = v;
                    }
                }
                #pragma unroll
                for (int it = 0; it < 8; it++) {
                    const int cid = it * 64 + lane;
                    const int row = cid >> 5, c4 = cid & 31;
                    f32x4 vv = *(const f32x4*)&scratchf[row * 132 + c4 * 4];
                    const int m = mBase + wm + mi * 16 + row;
                    *(f32x4*)&C[(int64_t)m * N + nBase + wn + c4 * 4] = vv;
                }
            }
        }

        __syncthreads();        // scratch reads done -> buf1 may be overwritten

        if (sub + 1 < NSUB) {
            // stage next-sub tile1 u0..u2 -> buf1, restore pipeline invariant
            stageU(sA0, sA1, 1, 0, 64); stageU(nB0, nB1, 1, 1, 64);
            stageU(sA0, sA1, 1, 2, 96);
            asm volatile("s_waitcnt vmcnt(6)" ::: "memory");
            __builtin_amdgcn_s_barrier();
            __builtin_amdgcn_sched_barrier(0);
            #pragma unroll
            for (int i = 0; i < 4; i++) aX[i] = *(const bf16x8*)&smem[aOff + i * 512];
            #pragma unroll
            for (int j = 0; j < 4; j++) bX[j] = *(const bf16x8*)&smem[8192 + bOff + j * 512];
            sB0 = nB0; sB1 = nB1; bx = bx + 1;
        }
    }
}

extern "C" void kernel_launch(void* const* d_in, const int* in_sizes, int n_in,
                              void* d_out, int out_size, void* d_ws, size_t ws_size,
                              hipStream_t stream) {
    const float* x  = (const float*)d_in[0];
    const float* W1 = (const float*)d_in[1];
    const float* A1 = (const float*)d_in[2];
    const float* B1 = (const float*)d_in[3];
    const float* W2 = (const float*)d_in[4];
    const float* A2 = (const float*)d_in[5];
    const float* B2 = (const float*)d_in[6];
    const int* adapter = (const int*)d_in[7];
    float* out = (float*)d_out;

    const int M = 16384, D = 1024, F = 4096;
    const int Nt1 = F / 256;                       // 16 N-tiles in GEMM1

    // ws layout (~184.5 MiB):
    bf16*  h   = (bf16*)d_ws;                      // M*F bf16 = 128 MiB
    bf16*  xb  = h + (size_t)M * F;                // M*D bf16 =  32 MiB
    bf16*  wb1 = xb + (size_t)M * D;               // F*D bf16 =   8 MiB
    bf16*  wb2 = wb1 + (size_t)F * D;              // D*F bf16 =   8 MiB
    float* t1  = (float*)(wb2 + (size_t)D * F);    // M*4 f32
    float* t2  = t1 + (size_t)M * 4;               // M*4 f32
    float* t2p = t2 + (size_t)M * 4;               // 32*M*4 f32 = 8 MiB

    // t1 = x @ A1a^T ; xb = bf16(x)
    lora1<<<M / 16, 256, 0, stream>>>(x, A1, adapter, t1, xb);
    // wb1 = bf16(W1), wb2 = bf16(W2)
    cvt_weights<<<(2 * F * D) / 2048, 256, 0, stream>>>(W1, wb1, F * D, W2, wb2, D * F);
    // h = relu(xb @ wb1^T + scale * t1 @ B1a^T); t2p partials (fused).
    // Persistent: 256 blocks, each sweeps 4 bx-subtiles at fixed by.
    gemm_p<true, bf16, true, 4><<<dim3(F / 1024, M / 256), 512, 0, stream>>>(
        xb, wb1, h, t1, B1, adapter, A2, t2p, M, F, D);
    // t2 = reduce(t2p)
    t2_reduce<<<(M * 4) / 256, 256, 0, stream>>>(t2p, t2, M, 2 * Nt1);
    // out = h @ wb2^T + scale * t2 @ B2a^T  -> f32 (256 blocks, 1 sub)
    gemm_p<false, float, false, 1><<<dim3(D / 256, M / 256), 512, 0, stream>>>(
        h, wb2, out, t2, B2, adapter, nullptr, nullptr, M, D, F);
}